// Round 6
// baseline (823.937 us; speedup 1.0000x reference)
//
#include <hip/hip_runtime.h>

// VectorQuantizer on MI355X — v7: MFMA approximate-then-verify.
// x: (32,256,32,32) fp32, codebook: (1024,256) fp32.
// Outputs concat: quantized (8388608 f32), vq_loss (1 f32), indices (32768 as f32).
//
// Indices must match numpy's grid-quantized distances exactly. Strategy:
//  - bf16-split dots on matrix cores: z=zhi+zlo, e=ehi+elo (RNE splits),
//    dot~ = MFMA(ehi,zhi)+MFMA(ehi,zlo)+MFMA(elo,zhi) in f32 accumulators.
//    |d~ - d32_exact| <= ~5e-5 (split residual ~3e-6 + accum rounding ~4e-6
//    + ulp(256)=3.05e-5 on the final subtract).
//  - track per-row (min1,k1,min2). gap>4e-4 (8x margin) => k1 provably equals
//    the exact argmin. gap<=4e-4 (~3-6% rows, includes all grid-ties) =>
//    exact rescore over all 1024 codes with v1's verified arithmetic
//    (f32 fma chains per 32-chunk, double chunk-sums ascending, strict-<).
//  - d~ uses the SAME fl32(fl32(T+U) - 2*fl32(dot)) formula with the SAME
//    Ts (numpy-order row norms) and u2 (numpy-order code norms).
// Geometry: 512 thr (8 waves), M=64/block, 512 blocks, 1 block/CU.
//  waves: mhalf=w&1 (32 m), kg=w>>1 (32 k of the 128-k tile). acc 2x2 16x16.
//  LDS 136KB: z_hi/z_lo [64][256] bf16 (64KB, quad-XOR-swizzled) + e dbuf
//  2x(hi,lo)[128k][64d] (64KB) staged via global_load_lds w/ pre-swizzled
//  source (v6-proven pattern) + reduction scratch.
// ws: u2 f32[1024] @0; e_hi bf16[1024*256] @4096; e_lo @4096+524288 (~1.05MB).

#define NUM_K 1024
#define DIM   256
#define HW    1024
#define N_TOT 32768
#define TM    64
#define LOSS_OFF 8388608
#define IDX_OFF  8388609
#define GAP_THRESH 4e-4f

typedef __attribute__((ext_vector_type(8))) short s16x8;
typedef __attribute__((ext_vector_type(4))) float f32x4;
typedef __attribute__((address_space(1))) const char GCHAR;
typedef __attribute__((address_space(3))) char LCHAR;

// numpy pairwise sum of squares over 256 elements, exact numpy order.
__device__ __forceinline__ float np_sumsq_256(const float* p, int stride) {
    float s[2];
    #pragma unroll
    for (int h = 0; h < 2; ++h) {
        const float* base = p + h * 128 * stride;
        float r[8];
        #pragma unroll
        for (int j = 0; j < 8; ++j) {
            float v = base[j * stride];
            r[j] = __fmul_rn(v, v);
        }
        for (int i = 8; i < 128; i += 8) {
            #pragma unroll
            for (int j = 0; j < 8; ++j) {
                float v = base[(i + j) * stride];
                r[j] = __fadd_rn(r[j], __fmul_rn(v, v));
            }
        }
        s[h] = __fadd_rn(__fadd_rn(__fadd_rn(r[0], r[1]), __fadd_rn(r[2], r[3])),
                         __fadd_rn(__fadd_rn(r[4], r[5]), __fadd_rn(r[6], r[7])));
    }
    return __fadd_rn(s[0], s[1]);
}

__device__ __forceinline__ ushort bf16_rne(float f) {
    unsigned u = __float_as_uint(f);
    unsigned r = (u + 0x7FFFu + ((u >> 16) & 1u)) >> 16;
    return (ushort)r;
}

__global__ __launch_bounds__(256) void u2_kernel(const float* __restrict__ cb,
                                                 float* __restrict__ u2) {
    int k = blockIdx.x * 256 + threadIdx.x;
    u2[k] = np_sumsq_256(cb + (size_t)k * DIM, 1);
}

// codebook -> bf16 hi/lo split arrays in workspace
__global__ __launch_bounds__(256) void cvt_kernel(const float* __restrict__ cb,
                                                  ushort* __restrict__ ehi,
                                                  ushort* __restrict__ elo) {
    int i = (blockIdx.x * 256 + threadIdx.x) * 4;   // 256 blocks cover 262144
    float4 v = *(const float4*)(cb + i);
    ushort h[4], l[4];
    const float* vf = (const float*)&v;
    #pragma unroll
    for (int j = 0; j < 4; ++j) {
        ushort hb = bf16_rne(vf[j]);
        float hf = __uint_as_float((unsigned)hb << 16);
        h[j] = hb;
        l[j] = bf16_rne(vf[j] - hf);   // exact residual (Sterbenz)
    }
    *(ushort4*)(ehi + i) = make_ushort4(h[0], h[1], h[2], h[3]);
    *(ushort4*)(elo + i) = make_ushort4(l[0], l[1], l[2], l[3]);
}

__global__ __launch_bounds__(512) void vq_main(const float* __restrict__ x,
                                               const float* __restrict__ cb,
                                               const float* __restrict__ u2g,
                                               const ushort* __restrict__ ehi,
                                               const ushort* __restrict__ elo,
                                               float* __restrict__ out) {
    __shared__ short z_hi[TM * DIM];       // 32KB [m][dquad^((m&7))] bf16
    __shared__ short z_lo[TM * DIM];       // 32KB
    __shared__ short ebuf[2 * 2 * 128 * 64]; // 64KB [buf][h][k][dq^(k&7)]
    __shared__ float Ts_s[TM];
    __shared__ float red_v1[256];
    __shared__ float red_v2[256];
    __shared__ int   red_k1[256];
    __shared__ float zrow_s[DIM];
    __shared__ int   bestk_s[TM];
    __shared__ int   flag_list[TM];
    __shared__ int   flag_cnt;
    __shared__ float wsum[8];

    const int t    = threadIdx.x;
    const int lane = t & 63;
    const int wv   = t >> 6;               // 0..7
    const int g    = blockIdx.x;           // 512 blocks
    const int n0   = g * TM;
    const int b    = n0 >> 10;
    const int r0   = n0 & (HW - 1);
    const size_t xbase = (size_t)b * (DIM * HW) + r0;

    if (t == 0) flag_cnt = 0;

    // staging constants (pre-swizzled global source, v6-proven pattern):
    // chunk Q=j*512+t -> LDS row k=Q>>3, phys quad p=t&7; content = ws quad
    // q = p ^ (k&7), with k&7 = (t>>3)&7 (j-invariant).
    const int q16 = (((t & 7) ^ ((t >> 3) & 7)) << 4);
    const int srow = t >> 3;               // 0..63 (j adds 64)
    const int wchunk = (t & 448) * 16;     // wave-uniform dst base

    auto stage = [&](int p, int buf) {
        const int kt = p >> 2, dqo = p & 3;
        #pragma unroll
        for (int h = 0; h < 2; ++h) {
            const ushort* wsrc = h ? elo : ehi;
            #pragma unroll
            for (int j = 0; j < 2; ++j) {
                const char* src = (const char*)wsrc
                    + (size_t)(kt * 128 + j * 64 + srow) * 512 + dqo * 128 + q16;
                char* dst = (char*)ebuf + (buf * 2 + h) * 16384
                    + j * 8192 + wchunk;
                __builtin_amdgcn_global_load_lds((GCHAR*)src, (LCHAR*)dst, 16, 0, 0);
            }
        }
    };

    stage(0, 0);   // overlap with z-staging below

    // ---- z staging: transpose [d][m] -> [m][d], split to bf16 hi/lo ----
    {
        const int mu = t & 15, du = t >> 5;        // 16 m-groups x 16 d-quads? no:
        // 512 threads: mu 0..15 (4 m each), duq = t>>4 (0..31 quads of 8 d)
        const int m0 = mu * 4;
        const int duq = t >> 4;                    // 0..31
        const int d0 = duq * 8;
        float4 xv[8];
        #pragma unroll
        for (int dd = 0; dd < 8; ++dd)
            xv[dd] = *(const float4*)(x + xbase + (size_t)(d0 + dd) * HW + m0);
        #pragma unroll
        for (int j = 0; j < 4; ++j) {
            const int m = m0 + j;
            s16x8 hv, lv;
            #pragma unroll
            for (int dd = 0; dd < 8; ++dd) {
                float f = ((const float*)&xv[dd])[j];
                ushort hb = bf16_rne(f);
                float hf = __uint_as_float((unsigned)hb << 16);
                hv[dd] = (short)hb;
                lv[dd] = (short)bf16_rne(f - hf);
            }
            const int off = m * 512 + ((duq ^ (m & 7)) << 4);
            *(s16x8*)((char*)z_hi + off) = hv;
            *(s16x8*)((char*)z_lo + off) = lv;
        }
        (void)mu; (void)du;
    }

    // ---- numpy-order ||z||^2 per row ----
    if (t < TM) Ts_s[t] = np_sumsq_256(x + xbase + t, HW);
    __syncthreads();   // z LDS + Ts + stage(0) all complete

    // ---- per-lane geometry ----
    const int lgrp  = lane >> 4;          // 0..3
    const int col   = lane & 15;
    const int mhalf = wv & 1;
    const int kg    = wv >> 1;            // 0..3
    const int mm0   = mhalf * 32 + col;   // mu=0 row
    const int mm1   = mm0 + 16;
    const int zxm   = (mm0 & 7) << 4;     // (mm1&7)==(mm0&7)
    const int kr0   = kg * 32 + col;      // local k row (tile of 128)
    const int kr1   = kr0 + 16;
    const int exk   = (kr0 & 7) << 4;     // same for kr1
    const float Ts0 = Ts_s[mm0];
    const float Ts1 = Ts_s[mm1];

    float v1a = 3.4e38f, v2a = 3.4e38f; int k1a = 0;
    float v1b = 3.4e38f, v2b = 3.4e38f; int k1b = 0;

    for (int kt = 0; kt < 8; ++kt) {
        f32x4 acc00 = {0.f,0.f,0.f,0.f}, acc01 = {0.f,0.f,0.f,0.f};
        f32x4 acc10 = {0.f,0.f,0.f,0.f}, acc11 = {0.f,0.f,0.f,0.f};

        for (int dqo = 0; dqo < 4; ++dqo) {
            const int p = kt * 4 + dqo;
            __syncthreads();              // stage(p) landed; prev readers done
            if (p + 1 < 32) stage(p + 1, (p + 1) & 1);
            const int cur = p & 1;
            const char* eb_h = (const char*)ebuf + (cur * 2 + 0) * 16384;
            const char* eb_l = (const char*)ebuf + (cur * 2 + 1) * 16384;

            #pragma unroll
            for (int dstep = 0; dstep < 2; ++dstep) {
                const int zo = dqo * 128 + dstep * 64 + lgrp * 16;
                const int eo = dstep * 64 + lgrp * 16;
                s16x8 zh0 = *(const s16x8*)((const char*)z_hi + mm0 * 512 + (zo ^ zxm));
                s16x8 zl0 = *(const s16x8*)((const char*)z_lo + mm0 * 512 + (zo ^ zxm));
                s16x8 zh1 = *(const s16x8*)((const char*)z_hi + mm1 * 512 + (zo ^ zxm));
                s16x8 zl1 = *(const s16x8*)((const char*)z_lo + mm1 * 512 + (zo ^ zxm));
                s16x8 eh0 = *(const s16x8*)(eb_h + kr0 * 128 + (eo ^ exk));
                s16x8 el0 = *(const s16x8*)(eb_l + kr0 * 128 + (eo ^ exk));
                s16x8 eh1 = *(const s16x8*)(eb_h + kr1 * 128 + (eo ^ exk));
                s16x8 el1 = *(const s16x8*)(eb_l + kr1 * 128 + (eo ^ exk));
                // D[k][m]: A=e (rows=k), B=z (cols=m). hihi + hilo + lohi.
                acc00 = __builtin_amdgcn_mfma_f32_16x16x32_bf16(eh0, zh0, acc00, 0, 0, 0);
                acc00 = __builtin_amdgcn_mfma_f32_16x16x32_bf16(eh0, zl0, acc00, 0, 0, 0);
                acc00 = __builtin_amdgcn_mfma_f32_16x16x32_bf16(el0, zh0, acc00, 0, 0, 0);
                acc01 = __builtin_amdgcn_mfma_f32_16x16x32_bf16(eh1, zh0, acc01, 0, 0, 0);
                acc01 = __builtin_amdgcn_mfma_f32_16x16x32_bf16(eh1, zl0, acc01, 0, 0, 0);
                acc01 = __builtin_amdgcn_mfma_f32_16x16x32_bf16(el1, zh0, acc01, 0, 0, 0);
                acc10 = __builtin_amdgcn_mfma_f32_16x16x32_bf16(eh0, zh1, acc10, 0, 0, 0);
                acc10 = __builtin_amdgcn_mfma_f32_16x16x32_bf16(eh0, zl1, acc10, 0, 0, 0);
                acc10 = __builtin_amdgcn_mfma_f32_16x16x32_bf16(el0, zh1, acc10, 0, 0, 0);
                acc11 = __builtin_amdgcn_mfma_f32_16x16x32_bf16(eh1, zh1, acc11, 0, 0, 0);
                acc11 = __builtin_amdgcn_mfma_f32_16x16x32_bf16(eh1, zl1, acc11, 0, 0, 0);
                acc11 = __builtin_amdgcn_mfma_f32_16x16x32_bf16(el1, zh1, acc11, 0, 0, 0);
            }
        }

        // ---- kt epilogue: d~ + min1/min2 tracking (k ascending per mu) ----
        #pragma unroll
        for (int s = 0; s < 2; ++s) {
            const int kb = kt * 128 + kg * 32 + s * 16 + lgrp * 4;
            float4 u4 = *(const float4*)(u2g + kb);
            const float* uf = (const float*)&u4;
            const f32x4 a0 = s ? acc01 : acc00;
            const f32x4 a1 = s ? acc11 : acc10;
            #pragma unroll
            for (int r = 0; r < 4; ++r) {
                const int kk = kb + r;
                {
                    float c   = __fmul_rn(2.0f, a0[r]);
                    float t1  = __fadd_rn(Ts0, uf[r]);
                    float d32 = __fsub_rn(t1, c);
                    if (d32 < v1a) { v2a = v1a; v1a = d32; k1a = kk; }
                    else if (d32 < v2a) v2a = d32;
                }
                {
                    float c   = __fmul_rn(2.0f, a1[r]);
                    float t1  = __fadd_rn(Ts1, uf[r]);
                    float d32 = __fsub_rn(t1, c);
                    if (d32 < v1b) { v2b = v1b; v1b = d32; k1b = kk; }
                    else if (d32 < v2b) v2b = d32;
                }
            }
        }
    }

    // ---- merge (v1,k1,v2) across the 4 lane-copies of each m-column ----
    #pragma unroll
    for (int off = 16; off < 64; off <<= 1) {
        float ov1 = __shfl_xor(v1a, off, 64);
        int   ok1 = __shfl_xor(k1a, off, 64);
        float ov2 = __shfl_xor(v2a, off, 64);
        if (ov1 < v1a || (ov1 == v1a && ok1 < k1a)) {
            v2a = fminf(v1a, ov2); v1a = ov1; k1a = ok1;
        } else v2a = fminf(v2a, ov1);
        ov1 = __shfl_xor(v1b, off, 64);
        ok1 = __shfl_xor(k1b, off, 64);
        ov2 = __shfl_xor(v2b, off, 64);
        if (ov1 < v1b || (ov1 == v1b && ok1 < k1b)) {
            v2b = fminf(v1b, ov2); v1b = ov1; k1b = ok1;
        } else v2b = fminf(v2b, ov1);
    }
    if (lane < 16) {
        red_v1[kg * 64 + mm0] = v1a; red_k1[kg * 64 + mm0] = k1a; red_v2[kg * 64 + mm0] = v2a;
        red_v1[kg * 64 + mm1] = v1b; red_k1[kg * 64 + mm1] = k1b; red_v2[kg * 64 + mm1] = v2b;
    }
    __syncthreads();

    // ---- final per-m merge across the 4 k-groups; flag small gaps ----
    if (t < TM) {
        float bv1 = red_v1[t], bv2 = red_v2[t]; int bk1 = red_k1[t];
        #pragma unroll
        for (int q = 1; q < 4; ++q) {
            float a1 = red_v1[q * 64 + t], a2 = red_v2[q * 64 + t];
            int ak1 = red_k1[q * 64 + t];
            if (a1 < bv1 || (a1 == bv1 && ak1 < bk1)) {
                bv2 = fminf(bv1, a2); bv1 = a1; bk1 = ak1;
            } else bv2 = fminf(bv2, a1);
        }
        bestk_s[t] = bk1;
        if (bv2 - bv1 < GAP_THRESH) {
            int slot = atomicAdd(&flag_cnt, 1);
            flag_list[slot] = t;
        }
    }
    __syncthreads();
    const int nflag = flag_cnt;

    // ---- exact rescore (v1's verified arithmetic) for flagged rows ----
    for (int fi = 0; fi < nflag; ++fi) {
        const int fm = flag_list[fi];
        __syncthreads();
        if (t < DIM) zrow_s[t] = x[xbase + (size_t)t * HW + fm];
        __syncthreads();
        float fv = 3.4e38f; int fk = 0;
        #pragma unroll
        for (int kk2 = 0; kk2 < 2; ++kk2) {
            const int k = t * 2 + kk2;
            const float* er = cb + (size_t)k * DIM;
            double accd = 0.0;
            for (int dc = 0; dc < 8; ++dc) {
                const float* zc = zrow_s + dc * 32;
                const float* ec = er + dc * 32;
                float af = 0.f;
                #pragma unroll
                for (int q = 0; q < 8; ++q) {
                    float4 e4 = *(const float4*)(ec + q * 4);
                    if (q == 0) af = __fmul_rn(zc[0], e4.x);
                    else        af = fmaf(zc[q * 4], e4.x, af);
                    af = fmaf(zc[q * 4 + 1], e4.y, af);
                    af = fmaf(zc[q * 4 + 2], e4.z, af);
                    af = fmaf(zc[q * 4 + 3], e4.w, af);
                }
                accd += (double)af;
            }
            float m32 = (float)accd;
            float c   = __fmul_rn(2.0f, m32);
            float t1  = __fadd_rn(Ts_s[fm], u2g[k]);
            float d32 = __fsub_rn(t1, c);
            if (d32 < fv) { fv = d32; fk = k; }   // ks ascend per thread
        }
        #pragma unroll
        for (int off = 1; off < 64; off <<= 1) {
            float ov = __shfl_xor(fv, off, 64);
            int   ok = __shfl_xor(fk, off, 64);
            if (ov < fv || (ov == fv && ok < fk)) { fv = ov; fk = ok; }
        }
        if (lane == 0) { red_v1[wv] = fv; red_k1[wv] = fk; }
        __syncthreads();
        if (t == 0) {
            float bfv = red_v1[0]; int bfk = red_k1[0];
            #pragma unroll
            for (int w2 = 1; w2 < 8; ++w2) {
                float v = red_v1[w2]; int k2 = red_k1[w2];
                if (v < bfv || (v == bfv && k2 < bfk)) { bfv = v; bfk = k2; }
            }
            bestk_s[fm] = bfk;
        }
    }
    __syncthreads();

    if (t < TM) out[IDX_OFF + n0 + t] = (float)bestk_s[t];

    // ---- epilogue: quantized output + fused loss ----
    float lsum = 0.f;
    {
        const int m  = t & 63;
        const int kq = bestk_s[m];
        const float* crow = cb + (size_t)kq * DIM;
        for (int c = (t >> 6); c < DIM; c += 8) {
            float qv = crow[c];
            float xv = x[xbase + (size_t)c * HW + m];
            float d  = qv - xv;
            lsum = fmaf(d, d, lsum);
            out[xbase + (size_t)c * HW + m] = qv;
        }
    }
    #pragma unroll
    for (int off = 32; off > 0; off >>= 1) lsum += __shfl_down(lsum, off, 64);
    if (lane == 0) wsum[wv] = lsum;
    __syncthreads();
    if (t == 0) {
        float s = __fadd_rn(__fadd_rn(__fadd_rn(wsum[0], wsum[1]),
                                      __fadd_rn(wsum[2], wsum[3])),
                            __fadd_rn(__fadd_rn(wsum[4], wsum[5]),
                                      __fadd_rn(wsum[6], wsum[7])));
        atomicAdd(out + LOSS_OFF, s * (1.25f / 8388608.0f));
    }
}

extern "C" void kernel_launch(void* const* d_in, const int* in_sizes, int n_in,
                              void* d_out, int out_size, void* d_ws, size_t ws_size,
                              hipStream_t stream) {
    const float* x  = (const float*)d_in[0];
    const float* cb = (const float*)d_in[1];
    float* out = (float*)d_out;
    float* u2  = (float*)d_ws;                                   // 4KB
    ushort* ehi = (ushort*)((char*)d_ws + 4096);                 // 512KB
    ushort* elo = (ushort*)((char*)d_ws + 4096 + 524288);        // 512KB

    hipMemsetAsync(out + LOSS_OFF, 0, sizeof(float), stream);
    u2_kernel<<<NUM_K / 256, 256, 0, stream>>>(cb, u2);
    cvt_kernel<<<256, 256, 0, stream>>>(cb, ehi, elo);
    vq_main<<<N_TOT / TM, 512, 0, stream>>>(x, cb, u2, ehi, elo, out);
}

// Round 7
// 802.888 us; speedup vs baseline: 1.0262x; 1.0262x over previous
//
#include <hip/hip_runtime.h>

// VectorQuantizer on MI355X — v8: MFMA approx-then-verify, re-engineered for
// the two HW walls proven in v1-v7: (a) the allocator refuses >128 VGPRs and
// spills (v2/v3/v7: 330-340MB scratch writes); (b) need >=2 blocks/CU for
// latency hiding (v7: 136KB LDS -> 1 block/CU -> MfmaUtil 2.7%).
//
// Strategy (v7's, validated correct there):
//  - bf16-split dots on matrix cores. v8 drops the elo term: dot~ =
//    ehi*(zhi+zlo) = ehi*z. Missing elo*z: rms ~1.9e-5 => d-error rms
//    ~3.7e-5 (~1.2 ulp at |d|~256). THRESH=5e-4 => 6.8-sigma allowance.
//  - per-row (min1,k1,min2); gap>=THRESH => k1 == exact argmin. gap<THRESH
//    (~5-7% rows, incl. all grid-ties) => exact rescore over all 1024 codes
//    with v1's verified arithmetic (f32 fma chains per 32-chunk, double
//    chunk-sums ascending, strict-< earliest-k).
//  - d~ uses the SAME fl32(fl32(T+U)-2*fl32(dot)) with the same Ts / u2.
// Geometry: 256 thr (4 waves), TM=32 rows, 1024 blocks. Wave tile 32k x 32m
// (2x2 16x16 acc = 16 VGPR). kt-tile 128 k, 64-d chunks, 32 phases.
// LDS 67KB => 2 blocks/CU: z_hi/z_lo [32m][256d] bf16 (32KB, 5-bit XOR
// swizzle) + ebuf 2x[128k][64d] bf16 (32KB, staged via global_load_lds with
// pre-swizzled source — v6-proven) + scratch.
// Live VGPR ~105 (6 frags=48 + acc 16 + track/addr) — under the 128 wall.
// ws: u2 f32[1024] @0; e_hi bf16[1024*256] @4096 (516KB total).

#define NUM_K 1024
#define DIM   256
#define HW    1024
#define N_TOT 32768
#define TM    32
#define LOSS_OFF 8388608
#define IDX_OFF  8388609
#define THRESH 5e-4f

typedef __attribute__((ext_vector_type(8))) short s16x8;
typedef __attribute__((ext_vector_type(4))) float f32x4;
typedef __attribute__((address_space(1))) const char GCHAR;
typedef __attribute__((address_space(3))) char LCHAR;

// numpy pairwise sum of squares over 256 elements, exact numpy order.
__device__ __forceinline__ float np_sumsq_256(const float* p, int stride) {
    float s[2];
    #pragma unroll
    for (int h = 0; h < 2; ++h) {
        const float* base = p + h * 128 * stride;
        float r[8];
        #pragma unroll
        for (int j = 0; j < 8; ++j) {
            float v = base[j * stride];
            r[j] = __fmul_rn(v, v);
        }
        for (int i = 8; i < 128; i += 8) {
            #pragma unroll
            for (int j = 0; j < 8; ++j) {
                float v = base[(i + j) * stride];
                r[j] = __fadd_rn(r[j], __fmul_rn(v, v));
            }
        }
        s[h] = __fadd_rn(__fadd_rn(__fadd_rn(r[0], r[1]), __fadd_rn(r[2], r[3])),
                         __fadd_rn(__fadd_rn(r[4], r[5]), __fadd_rn(r[6], r[7])));
    }
    return __fadd_rn(s[0], s[1]);
}

__device__ __forceinline__ ushort bf16_rne(float f) {
    unsigned u = __float_as_uint(f);
    unsigned r = (u + 0x7FFFu + ((u >> 16) & 1u)) >> 16;
    return (ushort)r;
}

__global__ __launch_bounds__(256) void u2_kernel(const float* __restrict__ cb,
                                                 float* __restrict__ u2) {
    int k = blockIdx.x * 256 + threadIdx.x;
    u2[k] = np_sumsq_256(cb + (size_t)k * DIM, 1);
}

__global__ __launch_bounds__(256) void cvt_kernel(const float* __restrict__ cb,
                                                  ushort* __restrict__ ehi) {
    int i = (blockIdx.x * 256 + threadIdx.x) * 4;   // 256 blocks cover 262144
    float4 v = *(const float4*)(cb + i);
    const float* vf = (const float*)&v;
    ushort h[4];
    #pragma unroll
    for (int j = 0; j < 4; ++j) h[j] = bf16_rne(vf[j]);
    *(ushort4*)(ehi + i) = make_ushort4(h[0], h[1], h[2], h[3]);
}

__global__ __launch_bounds__(256) void vq_main(const float* __restrict__ x,
                                               const float* __restrict__ cb,
                                               const float* __restrict__ u2g,
                                               const ushort* __restrict__ ehi,
                                               float* __restrict__ out) {
    __shared__ __align__(16) short z_hi[TM * DIM];      // 16 KB [m][slot^(m&31)]
    __shared__ __align__(16) short z_lo[TM * DIM];      // 16 KB
    __shared__ __align__(16) short ebuf[2 * 128 * 64];  // 32 KB [buf][k][slot^(k&7)]
    __shared__ float Ts_s[TM];
    __shared__ float red_v1[128], red_v2[128];
    __shared__ int   red_k1[128];
    __shared__ float zrow_s[DIM];
    __shared__ int   bestk_s[TM];
    __shared__ int   flag_list[TM];
    __shared__ int   flag_cnt;
    __shared__ float wsum[4];

    const int t    = threadIdx.x;
    const int lane = t & 63;
    const int wv   = t >> 6;               // 0..3
    const int g    = blockIdx.x;           // 1024 blocks
    const int n0   = g * TM;
    const int b    = n0 >> 10;
    const int r0   = n0 & (HW - 1);
    const size_t xbase = (size_t)b * (DIM * HW) + r0;

    if (t == 0) flag_cnt = 0;

    // ---- e staging map (v6-proven): chunk c=j*256+t -> row k=j*32+(t>>3),
    // phys slot p=t&7; content = global slot q = p^(k&7) = (t&7)^((t>>3)&7).
    const int q16  = (((t & 7) ^ ((t >> 3) & 7)) << 4);
    const int srow = t >> 3;               // 0..31
    const int wub  = (t & 192) * 16;       // wave-uniform dst base (wv*1024)

    auto stage = [&](int p, int buf) {
        const int ktn = p >> 2, d4n = p & 3;
        #pragma unroll
        for (int j = 0; j < 4; ++j) {
            const char* src = (const char*)ehi
                + (size_t)(ktn * 128 + j * 32 + srow) * 512 + d4n * 128 + q16;
            char* dst = (char*)ebuf + buf * 16384 + j * 4096 + wub;
            __builtin_amdgcn_global_load_lds((GCHAR*)src, (LCHAR*)dst, 16, 0, 0);
        }
    };

    stage(0, 0);   // overlaps the z-staging below

    // ---- z staging: [d][m] -> [m][d] bf16 hi/lo, 5-bit XOR slot swizzle ----
    {
        const int zd0 = (t >> 3) * 8;      // d-octet base (32 groups)
        const int zm0 = (t & 7) * 4;       // 4 m's
        float4 xv[8];
        #pragma unroll
        for (int dd = 0; dd < 8; ++dd)
            xv[dd] = *(const float4*)(x + xbase + (size_t)(zd0 + dd) * HW + zm0);
        #pragma unroll
        for (int j = 0; j < 4; ++j) {
            const int m = zm0 + j;
            s16x8 hv, lv;
            #pragma unroll
            for (int dd = 0; dd < 8; ++dd) {
                float f = ((const float*)&xv[dd])[j];
                ushort hb = bf16_rne(f);
                float hf = __uint_as_float((unsigned)hb << 16);
                hv[dd] = (short)hb;
                lv[dd] = (short)bf16_rne(f - hf);
            }
            const int byte = m * 512 + ((((zd0 >> 3) ^ m) & 31) << 4);
            *(s16x8*)((char*)z_hi + byte) = hv;
            *(s16x8*)((char*)z_lo + byte) = lv;
        }
    }

    // ---- numpy-order ||z||^2 per row ----
    if (t < TM) Ts_s[t] = np_sumsq_256(x + xbase + t, HW);
    __syncthreads();   // z LDS + Ts + stage(0) (vmcnt drained at barrier)

    // ---- per-lane geometry ----
    const int col  = lane & 15;
    const int lg   = lane >> 4;            // 0..3
    const int ebA  = (wv * 32 + col) * 128;        // e kf=0 row byte base
    const int ebB  = ebA + 16 * 128;               // kf=1
    const int eswz = (col & 7) << 4;
    const int zmA  = col, zmB = col + 16;
    const float TsA = Ts_s[zmA];
    const float TsB = Ts_s[zmB];

    float vA1 = 3.4e38f, vA2 = 3.4e38f; int kA1 = 0;
    float vB1 = 3.4e38f, vB2 = 3.4e38f; int kB1 = 0;

    for (int kt = 0; kt < 8; ++kt) {
        f32x4 a00 = {0.f,0.f,0.f,0.f}, a01 = {0.f,0.f,0.f,0.f};
        f32x4 a10 = {0.f,0.f,0.f,0.f}, a11 = {0.f,0.f,0.f,0.f};

        for (int d4 = 0; d4 < 4; ++d4) {
            const int p = kt * 4 + d4;
            __syncthreads();               // stage(p) landed; prev buf readers done
            if (p + 1 < 32) stage(p + 1, (p + 1) & 1);
            const char* ebp = (const char*)ebuf + (p & 1) * 16384;

            #pragma unroll
            for (int ds = 0; ds < 2; ++ds) {
                const int zsl   = d4 * 8 + ds * 4 + lg;
                const int esl16 = (ds * 4 + lg) << 4;
                s16x8 eh0 = *(const s16x8*)(ebp + ebA + (esl16 ^ eswz));
                s16x8 eh1 = *(const s16x8*)(ebp + ebB + (esl16 ^ eswz));
                const int zoA = zmA * 512 + (((zsl ^ zmA) & 31) << 4);
                const int zoB = zmB * 512 + (((zsl ^ zmB) & 31) << 4);
                s16x8 zh0 = *(const s16x8*)((const char*)z_hi + zoA);
                s16x8 zl0 = *(const s16x8*)((const char*)z_lo + zoA);
                s16x8 zh1 = *(const s16x8*)((const char*)z_hi + zoB);
                s16x8 zl1 = *(const s16x8*)((const char*)z_lo + zoB);
                // D[k][m]: A=e rows=k, B=z cols=m (v7-verified orientation)
                a00 = __builtin_amdgcn_mfma_f32_16x16x32_bf16(eh0, zh0, a00, 0, 0, 0);
                a00 = __builtin_amdgcn_mfma_f32_16x16x32_bf16(eh0, zl0, a00, 0, 0, 0);
                a01 = __builtin_amdgcn_mfma_f32_16x16x32_bf16(eh0, zh1, a01, 0, 0, 0);
                a01 = __builtin_amdgcn_mfma_f32_16x16x32_bf16(eh0, zl1, a01, 0, 0, 0);
                a10 = __builtin_amdgcn_mfma_f32_16x16x32_bf16(eh1, zh0, a10, 0, 0, 0);
                a10 = __builtin_amdgcn_mfma_f32_16x16x32_bf16(eh1, zl0, a10, 0, 0, 0);
                a11 = __builtin_amdgcn_mfma_f32_16x16x32_bf16(eh1, zh1, a11, 0, 0, 0);
                a11 = __builtin_amdgcn_mfma_f32_16x16x32_bf16(eh1, zl1, a11, 0, 0, 0);
            }
        }

        // ---- kt epilogue: d~ = fl32(fl32(T+U) - 2*fl32(dot)); min1/min2 ----
        const int kb = kt * 128 + wv * 32 + lg * 4;
        float4 u40 = *(const float4*)(u2g + kb);
        float4 u41 = *(const float4*)(u2g + kb + 16);
        const float* u0f = (const float*)&u40;
        const float* u1f = (const float*)&u41;
        #pragma unroll
        for (int r = 0; r < 4; ++r) {
            const int kk = kb + r;
            float c, t1, d32;
            c = __fmul_rn(2.0f, a00[r]); t1 = __fadd_rn(TsA, u0f[r]); d32 = __fsub_rn(t1, c);
            if (d32 < vA1) { vA2 = vA1; vA1 = d32; kA1 = kk; } else if (d32 < vA2) vA2 = d32;
            c = __fmul_rn(2.0f, a01[r]); t1 = __fadd_rn(TsB, u0f[r]); d32 = __fsub_rn(t1, c);
            if (d32 < vB1) { vB2 = vB1; vB1 = d32; kB1 = kk; } else if (d32 < vB2) vB2 = d32;
        }
        #pragma unroll
        for (int r = 0; r < 4; ++r) {
            const int kk = kb + 16 + r;
            float c, t1, d32;
            c = __fmul_rn(2.0f, a10[r]); t1 = __fadd_rn(TsA, u1f[r]); d32 = __fsub_rn(t1, c);
            if (d32 < vA1) { vA2 = vA1; vA1 = d32; kA1 = kk; } else if (d32 < vA2) vA2 = d32;
            c = __fmul_rn(2.0f, a11[r]); t1 = __fadd_rn(TsB, u1f[r]); d32 = __fsub_rn(t1, c);
            if (d32 < vB1) { vB2 = vB1; vB1 = d32; kB1 = kk; } else if (d32 < vB2) vB2 = d32;
        }
    }

    // ---- merge (v1,k1,v2) across the 4 lane-groups holding the same m ----
    #pragma unroll
    for (int off = 16; off < 64; off <<= 1) {
        float ov1 = __shfl_xor(vA1, off, 64);
        int   ok1 = __shfl_xor(kA1, off, 64);
        float ov2 = __shfl_xor(vA2, off, 64);
        if (ov1 < vA1 || (ov1 == vA1 && ok1 < kA1)) {
            vA2 = fminf(vA1, ov2); vA1 = ov1; kA1 = ok1;
        } else vA2 = fminf(vA2, ov1);
        ov1 = __shfl_xor(vB1, off, 64);
        ok1 = __shfl_xor(kB1, off, 64);
        ov2 = __shfl_xor(vB2, off, 64);
        if (ov1 < vB1 || (ov1 == vB1 && ok1 < kB1)) {
            vB2 = fminf(vB1, ov2); vB1 = ov1; kB1 = ok1;
        } else vB2 = fminf(vB2, ov1);
    }
    if (lane < 16) {
        red_v1[wv * 32 + zmA] = vA1; red_k1[wv * 32 + zmA] = kA1; red_v2[wv * 32 + zmA] = vA2;
        red_v1[wv * 32 + zmB] = vB1; red_k1[wv * 32 + zmB] = kB1; red_v2[wv * 32 + zmB] = vB2;
    }
    __syncthreads();

    // ---- final per-m merge across 4 waves (= k-groups); flag small gaps ----
    if (t < TM) {
        float bv1 = red_v1[t], bv2 = red_v2[t]; int bk1 = red_k1[t];
        #pragma unroll
        for (int q = 1; q < 4; ++q) {
            float a1 = red_v1[q * 32 + t], a2 = red_v2[q * 32 + t];
            int ak1 = red_k1[q * 32 + t];
            if (a1 < bv1 || (a1 == bv1 && ak1 < bk1)) {
                bv2 = fminf(bv1, a2); bv1 = a1; bk1 = ak1;
            } else bv2 = fminf(bv2, a1);
        }
        bestk_s[t] = bk1;
        if (bv2 - bv1 < THRESH) {
            int slot = atomicAdd(&flag_cnt, 1);
            flag_list[slot] = t;
        }
    }
    __syncthreads();
    const int nflag = flag_cnt;

    // ---- exact rescore (v1's verified arithmetic) for flagged rows ----
    for (int fi = 0; fi < nflag; ++fi) {
        const int fm = flag_list[fi];
        if (t < 64) {
            #pragma unroll
            for (int q = 0; q < 4; ++q)
                zrow_s[t * 4 + q] = x[xbase + (size_t)(t * 4 + q) * HW + fm];
        }
        __syncthreads();
        float fv = 3.4e38f; int fk = 0;
        double accd[4] = {0.0, 0.0, 0.0, 0.0};
        for (int dc = 0; dc < 8; ++dc) {
            float af[4];
            #pragma unroll
            for (int q = 0; q < 8; ++q) {
                const float z0 = zrow_s[dc * 32 + q * 4 + 0];
                const float z1 = zrow_s[dc * 32 + q * 4 + 1];
                const float z2 = zrow_s[dc * 32 + q * 4 + 2];
                const float z3 = zrow_s[dc * 32 + q * 4 + 3];
                #pragma unroll
                for (int j = 0; j < 4; ++j) {
                    float4 e4 = *(const float4*)(cb + (size_t)(j * 256 + t) * DIM + dc * 32 + q * 4);
                    if (q == 0) af[j] = __fmul_rn(z0, e4.x);
                    else        af[j] = fmaf(z0, e4.x, af[j]);
                    af[j] = fmaf(z1, e4.y, af[j]);
                    af[j] = fmaf(z2, e4.z, af[j]);
                    af[j] = fmaf(z3, e4.w, af[j]);
                }
            }
            #pragma unroll
            for (int j = 0; j < 4; ++j) accd[j] += (double)af[j];
        }
        #pragma unroll
        for (int j = 0; j < 4; ++j) {
            const int k = j * 256 + t;          // ascending per thread
            float m32 = (float)accd[j];
            float c   = __fmul_rn(2.0f, m32);
            float t1  = __fadd_rn(Ts_s[fm], u2g[k]);
            float d32 = __fsub_rn(t1, c);
            if (d32 < fv) { fv = d32; fk = k; }
        }
        #pragma unroll
        for (int off = 1; off < 64; off <<= 1) {
            float ov = __shfl_xor(fv, off, 64);
            int   ok = __shfl_xor(fk, off, 64);
            if (ov < fv || (ov == fv && ok < fk)) { fv = ov; fk = ok; }
        }
        if (lane == 0) { red_v1[wv] = fv; red_k1[wv] = fk; }
        __syncthreads();
        if (t == 0) {
            float bfv = red_v1[0]; int bfk = red_k1[0];
            #pragma unroll
            for (int w2 = 1; w2 < 4; ++w2) {
                float v = red_v1[w2]; int k2 = red_k1[w2];
                if (v < bfv || (v == bfv && k2 < bfk)) { bfv = v; bfk = k2; }
            }
            bestk_s[fm] = bfk;
        }
    }
    __syncthreads();

    if (t < TM) out[IDX_OFF + n0 + t] = (float)bestk_s[t];

    // ---- epilogue: quantized output + fused loss ----
    float lsum = 0.f;
    {
        const int m  = t & 31;
        const int kq = bestk_s[m];
        const float* crow = cb + (size_t)kq * DIM;
        for (int c = (t >> 5); c < DIM; c += 8) {
            float qv = crow[c];
            float xv = x[xbase + (size_t)c * HW + m];
            float d  = qv - xv;
            lsum = fmaf(d, d, lsum);
            out[xbase + (size_t)c * HW + m] = qv;
        }
    }
    #pragma unroll
    for (int off = 32; off > 0; off >>= 1) lsum += __shfl_down(lsum, off, 64);
    if (lane == 0) wsum[wv] = lsum;
    __syncthreads();
    if (t == 0) {
        float s = __fadd_rn(__fadd_rn(wsum[0], wsum[1]), __fadd_rn(wsum[2], wsum[3]));
        atomicAdd(out + LOSS_OFF, s * (1.25f / 8388608.0f));
    }
}

extern "C" void kernel_launch(void* const* d_in, const int* in_sizes, int n_in,
                              void* d_out, int out_size, void* d_ws, size_t ws_size,
                              hipStream_t stream) {
    const float* x  = (const float*)d_in[0];
    const float* cb = (const float*)d_in[1];
    float* out = (float*)d_out;
    float* u2  = (float*)d_ws;                        // 4 KB
    ushort* ehi = (ushort*)((char*)d_ws + 4096);      // 512 KB

    hipMemsetAsync(out + LOSS_OFF, 0, sizeof(float), stream);
    u2_kernel<<<NUM_K / 256, 256, 0, stream>>>(cb, u2);
    cvt_kernel<<<256, 256, 0, stream>>>(cb, ehi);
    vq_main<<<N_TOT / TM, 256, 0, stream>>>(x, cb, u2, ehi, out);
}

// Round 8
// 308.366 us; speedup vs baseline: 2.6719x; 2.6037x over previous
//
#include <hip/hip_runtime.h>

// VectorQuantizer on MI355X — v9: MFMA approx-then-verify (v7/v8 math, passed)
// re-engineered around the two measured walls:
//  (a) >128 VGPR spills (v2/v3/v7) — v9 live set ~90.
//  (b) v8's 68.6KB LDS -> 1 block/CU (Occupancy 13.6%) -> everything
//      latency-serialized (VALU 6%, Mfma 1.8%). v9: 49.6KB -> 3 blocks/CU.
// Strategy:
//  - bf16-split dots on matrix cores: dot~ = ehi*zhi + ehi*zlo (f32 accum).
//    |d~ - d32| ~ 2.5e-5 rms (dominated by missing elo*z). THRESH=2e-4 is
//    an 8-sigma allowance on the top-2 gap -> provable argmin transfer.
//  - per-row (min1,k1,min2); gap<THRESH (incl. all grid ties) -> exact
//    rescore with v1's verified arithmetic (fp32 fma chains per 32-chunk,
//    double chunk-sums ascending, fl32(fl32(T+U)-2*fl32(dot)), strict-<
//    earliest-k). Rescore reads cbT[d][k] (transposed, ws) so lanes are
//    k-consecutive = coalesced (v8 read cb rows uncoalesced: 64 lines/instr).
// Geometry: 256 thr (4 waves), TM=32 rows, 1024 blocks. Wave tile 32k x 32m
// (2x2 16x16 acc). 64 phases: [128k x 32d] e-tiles, 8KB, double-buffered via
// global_load_lds with pre-swizzled source (v6-proven). z_hi/z_lo resident
// [32m][256d] bf16, octet-XOR swizzle.
// ws: u2 f32[1024] @0; ehi bf16[256K] @4096; cbT f32[256][1024] @528384.

#define NUM_K 1024
#define DIM   256
#define HW    1024
#define N_TOT 32768
#define TM    32
#define LOSS_OFF 8388608
#define IDX_OFF  8388609
#define THRESH 2e-4f

typedef __attribute__((ext_vector_type(8))) short s16x8;
typedef __attribute__((ext_vector_type(4))) float f32x4;
typedef __attribute__((address_space(1))) const char GCHAR;
typedef __attribute__((address_space(3))) char LCHAR;

// numpy pairwise sum of squares over 256 elements, exact numpy order.
__device__ __forceinline__ float np_sumsq_256(const float* p, int stride) {
    float s[2];
    #pragma unroll
    for (int h = 0; h < 2; ++h) {
        const float* base = p + h * 128 * stride;
        float r[8];
        #pragma unroll
        for (int j = 0; j < 8; ++j) {
            float v = base[j * stride];
            r[j] = __fmul_rn(v, v);
        }
        for (int i = 8; i < 128; i += 8) {
            #pragma unroll
            for (int j = 0; j < 8; ++j) {
                float v = base[(i + j) * stride];
                r[j] = __fadd_rn(r[j], __fmul_rn(v, v));
            }
        }
        s[h] = __fadd_rn(__fadd_rn(__fadd_rn(r[0], r[1]), __fadd_rn(r[2], r[3])),
                         __fadd_rn(__fadd_rn(r[4], r[5]), __fadd_rn(r[6], r[7])));
    }
    return __fadd_rn(s[0], s[1]);
}

__device__ __forceinline__ ushort bf16_rne(float f) {
    unsigned u = __float_as_uint(f);
    unsigned r = (u + 0x7FFFu + ((u >> 16) & 1u)) >> 16;
    return (ushort)r;
}

__global__ __launch_bounds__(256) void u2_kernel(const float* __restrict__ cb,
                                                 float* __restrict__ u2) {
    int k = blockIdx.x * 256 + threadIdx.x;
    u2[k] = np_sumsq_256(cb + (size_t)k * DIM, 1);
}

// codebook -> bf16-hi array + fp32 transpose cbT[d][k]
__global__ __launch_bounds__(256) void cvt_kernel(const float* __restrict__ cb,
                                                  ushort* __restrict__ ehi,
                                                  float* __restrict__ cbT) {
    int i = (blockIdx.x * 256 + threadIdx.x) * 4;   // 256 blocks cover 262144
    float4 v = *(const float4*)(cb + i);
    const float* vf = (const float*)&v;
    ushort h[4];
    const int k  = i >> 8;
    const int d0 = i & 255;
    #pragma unroll
    for (int j = 0; j < 4; ++j) {
        h[j] = bf16_rne(vf[j]);
        cbT[(size_t)(d0 + j) * NUM_K + k] = vf[j];
    }
    *(ushort4*)(ehi + i) = make_ushort4(h[0], h[1], h[2], h[3]);
}

__global__ __launch_bounds__(256) void vq_main(const float* __restrict__ x,
                                               const float* __restrict__ cb,
                                               const float* __restrict__ u2g,
                                               const ushort* __restrict__ ehi,
                                               const float* __restrict__ cbT,
                                               float* __restrict__ out) {
    __shared__ __align__(16) short z_hi[TM * DIM];      // 16 KB [m][oct^(m&31)]
    __shared__ __align__(16) short z_lo[TM * DIM];      // 16 KB
    __shared__ __align__(16) short ebuf[2 * 128 * 32];  // 16 KB [buf][k][oct^(k&3)]
    __shared__ float Ts_s[TM];
    __shared__ int   bestk_s[TM];
    __shared__ int   flag_list[TM];
    __shared__ int   flag_cnt;
    __shared__ float wsum[4];
    // post-main-loop aliases into ebuf (barrier-separated):
    float* zrow_s = (float*)ebuf;                        // 1 KB
    float* red_v1 = (float*)((char*)ebuf + 1024);        // 512 B [4][32]
    float* red_v2 = (float*)((char*)ebuf + 1536);        // 512 B
    int*   red_k1 = (int*)  ((char*)ebuf + 2048);        // 512 B
    float* rr_v   = (float*)((char*)ebuf + 2560);        // 16 B [4]
    int*   rr_k   = (int*)  ((char*)ebuf + 2576);        // 16 B [4]

    const int t    = threadIdx.x;
    const int lane = t & 63;
    const int wv   = t >> 6;               // 0..3
    const int g    = blockIdx.x;           // 1024 blocks
    const int n0   = g * TM;
    const int b    = n0 >> 10;
    const int r0   = n0 & (HW - 1);
    const size_t xbase = (size_t)b * (DIM * HW) + r0;

    if (t == 0) flag_cnt = 0;

    // ---- e staging map: chunk c=j*256+t -> row r=c>>2 (0..127 over j),
    // phys slot p4=c&3; content octet q = p4 ^ (r&3) = (t&3)^((t>>2)&3).
    const int q16  = (((t & 3) ^ ((t >> 2) & 3)) << 4);
    const int srow = t >> 2;               // 0..63 (j=1 adds 64)
    const int wub  = (t & 192) * 16;       // wave-uniform dst base

    auto stage = [&](int p, int buf) {
        const int ktn = p >> 3, dcn = p & 7;
        #pragma unroll
        for (int j = 0; j < 2; ++j) {
            const char* src = (const char*)ehi
                + (size_t)(ktn * 128 + j * 64 + srow) * 512 + dcn * 64 + q16;
            char* dst = (char*)ebuf + buf * 8192 + j * 4096 + wub;
            __builtin_amdgcn_global_load_lds((GCHAR*)src, (LCHAR*)dst, 16, 0, 0);
        }
    };

    stage(0, 0);   // overlaps the z-staging below

    // ---- z staging: [d][m] -> [m][oct] bf16 hi/lo, octet-XOR swizzle ----
    {
        const int oct = t >> 3;            // d-octet 0..31
        const int zd0 = oct * 8;
        const int zm0 = (t & 7) * 4;       // 4 m's
        float4 xv[8];
        #pragma unroll
        for (int dd = 0; dd < 8; ++dd)
            xv[dd] = *(const float4*)(x + xbase + (size_t)(zd0 + dd) * HW + zm0);
        #pragma unroll
        for (int j = 0; j < 4; ++j) {
            const int m = zm0 + j;
            s16x8 hv, lv;
            #pragma unroll
            for (int dd = 0; dd < 8; ++dd) {
                float f = ((const float*)&xv[dd])[j];
                ushort hb = bf16_rne(f);
                float hf = __uint_as_float((unsigned)hb << 16);
                hv[dd] = (short)hb;
                lv[dd] = (short)bf16_rne(f - hf);
            }
            const int byte = m * 512 + (((oct ^ m) & 31) << 4);
            *(s16x8*)((char*)z_hi + byte) = hv;
            *(s16x8*)((char*)z_lo + byte) = lv;
        }
    }

    // ---- numpy-order ||z||^2 per row ----
    if (t < TM) Ts_s[t] = np_sumsq_256(x + xbase + t, HW);
    __syncthreads();   // z LDS + Ts + stage(0) complete

    // ---- per-lane geometry ----
    const int col  = lane & 15;
    const int lg   = lane >> 4;            // 0..3 (k-octet of the MFMA frag)
    const int ebA  = (wv * 32 + col) * 64;         // e row byte base (kf=0)
    const int ebB  = ebA + 16 * 64;                // kf=1
    const int eswz = (col & 3) << 4;
    const int zmA  = col, zmB = col + 16;
    const float TsA = Ts_s[zmA];
    const float TsB = Ts_s[zmB];

    float vA1 = 3.4e38f, vA2 = 3.4e38f; int kA1 = 0;
    float vB1 = 3.4e38f, vB2 = 3.4e38f; int kB1 = 0;

    for (int kt = 0; kt < 8; ++kt) {
        f32x4 a00 = {0.f,0.f,0.f,0.f}, a01 = {0.f,0.f,0.f,0.f};
        f32x4 a10 = {0.f,0.f,0.f,0.f}, a11 = {0.f,0.f,0.f,0.f};

        for (int dc = 0; dc < 8; ++dc) {
            const int p = kt * 8 + dc;
            __syncthreads();               // stage(p) drained; prev buf readers done
            if (p + 1 < 64) stage(p + 1, (p + 1) & 1);
            const char* ebp = (const char*)ebuf + (p & 1) * 8192;

            const int eoff = (lg << 4) ^ eswz;
            s16x8 eh0 = *(const s16x8*)(ebp + ebA + eoff);
            s16x8 eh1 = *(const s16x8*)(ebp + ebB + eoff);
            const int oct = dc * 4 + lg;
            const int zoA = zmA * 512 + (((oct ^ zmA) & 31) << 4);
            const int zoB = zmB * 512 + (((oct ^ zmB) & 31) << 4);
            s16x8 zh0 = *(const s16x8*)((const char*)z_hi + zoA);
            s16x8 zl0 = *(const s16x8*)((const char*)z_lo + zoA);
            s16x8 zh1 = *(const s16x8*)((const char*)z_hi + zoB);
            s16x8 zl1 = *(const s16x8*)((const char*)z_lo + zoB);
            // D[k][m]: A=e rows=k, B=z cols=m (v7/v8-verified orientation)
            a00 = __builtin_amdgcn_mfma_f32_16x16x32_bf16(eh0, zh0, a00, 0, 0, 0);
            a00 = __builtin_amdgcn_mfma_f32_16x16x32_bf16(eh0, zl0, a00, 0, 0, 0);
            a01 = __builtin_amdgcn_mfma_f32_16x16x32_bf16(eh0, zh1, a01, 0, 0, 0);
            a01 = __builtin_amdgcn_mfma_f32_16x16x32_bf16(eh0, zl1, a01, 0, 0, 0);
            a10 = __builtin_amdgcn_mfma_f32_16x16x32_bf16(eh1, zh0, a10, 0, 0, 0);
            a10 = __builtin_amdgcn_mfma_f32_16x16x32_bf16(eh1, zl0, a10, 0, 0, 0);
            a11 = __builtin_amdgcn_mfma_f32_16x16x32_bf16(eh1, zh1, a11, 0, 0, 0);
            a11 = __builtin_amdgcn_mfma_f32_16x16x32_bf16(eh1, zl1, a11, 0, 0, 0);
        }

        // ---- kt epilogue: d~ = fl32(fl32(T+U) - 2*fl32(dot)); min1/min2 ----
        const int kb = kt * 128 + wv * 32 + lg * 4;
        float4 u40 = *(const float4*)(u2g + kb);
        float4 u41 = *(const float4*)(u2g + kb + 16);
        const float* u0f = (const float*)&u40;
        const float* u1f = (const float*)&u41;
        #pragma unroll
        for (int r = 0; r < 4; ++r) {
            const int kk = kb + r;
            float c, t1, d32;
            c = __fmul_rn(2.0f, a00[r]); t1 = __fadd_rn(TsA, u0f[r]); d32 = __fsub_rn(t1, c);
            if (d32 < vA1) { vA2 = vA1; vA1 = d32; kA1 = kk; } else if (d32 < vA2) vA2 = d32;
            c = __fmul_rn(2.0f, a01[r]); t1 = __fadd_rn(TsB, u0f[r]); d32 = __fsub_rn(t1, c);
            if (d32 < vB1) { vB2 = vB1; vB1 = d32; kB1 = kk; } else if (d32 < vB2) vB2 = d32;
        }
        #pragma unroll
        for (int r = 0; r < 4; ++r) {
            const int kk = kb + 16 + r;
            float c, t1, d32;
            c = __fmul_rn(2.0f, a10[r]); t1 = __fadd_rn(TsA, u1f[r]); d32 = __fsub_rn(t1, c);
            if (d32 < vA1) { vA2 = vA1; vA1 = d32; kA1 = kk; } else if (d32 < vA2) vA2 = d32;
            c = __fmul_rn(2.0f, a11[r]); t1 = __fadd_rn(TsB, u1f[r]); d32 = __fsub_rn(t1, c);
            if (d32 < vB1) { vB2 = vB1; vB1 = d32; kB1 = kk; } else if (d32 < vB2) vB2 = d32;
        }
    }

    __syncthreads();   // last phase's ebuf reads done -> aliases safe

    // ---- merge (v1,k1,v2) across the 4 lane-groups holding the same m ----
    #pragma unroll
    for (int off = 16; off < 64; off <<= 1) {
        float ov1 = __shfl_xor(vA1, off, 64);
        int   ok1 = __shfl_xor(kA1, off, 64);
        float ov2 = __shfl_xor(vA2, off, 64);
        if (ov1 < vA1 || (ov1 == vA1 && ok1 < kA1)) {
            vA2 = fminf(vA1, ov2); vA1 = ov1; kA1 = ok1;
        } else vA2 = fminf(vA2, ov1);
        ov1 = __shfl_xor(vB1, off, 64);
        ok1 = __shfl_xor(kB1, off, 64);
        ov2 = __shfl_xor(vB2, off, 64);
        if (ov1 < vB1 || (ov1 == vB1 && ok1 < kB1)) {
            vB2 = fminf(vB1, ov2); vB1 = ov1; kB1 = ok1;
        } else vB2 = fminf(vB2, ov1);
    }
    if (lane < 16) {
        red_v1[wv * 32 + zmA] = vA1; red_k1[wv * 32 + zmA] = kA1; red_v2[wv * 32 + zmA] = vA2;
        red_v1[wv * 32 + zmB] = vB1; red_k1[wv * 32 + zmB] = kB1; red_v2[wv * 32 + zmB] = vB2;
    }
    __syncthreads();

    // ---- final per-m merge across 4 waves (= k-groups); flag small gaps ----
    if (t < TM) {
        float bv1 = red_v1[t], bv2 = red_v2[t]; int bk1 = red_k1[t];
        #pragma unroll
        for (int q = 1; q < 4; ++q) {
            float a1 = red_v1[q * 32 + t], a2 = red_v2[q * 32 + t];
            int ak1 = red_k1[q * 32 + t];
            if (a1 < bv1 || (a1 == bv1 && ak1 < bk1)) {
                bv2 = fminf(bv1, a2); bv1 = a1; bk1 = ak1;
            } else bv2 = fminf(bv2, a1);
        }
        bestk_s[t] = bk1;
        if (bv2 - bv1 < THRESH) {
            int slot = atomicAdd(&flag_cnt, 1);
            flag_list[slot] = t;
        }
    }
    __syncthreads();
    const int nflag = flag_cnt;

    // ---- exact rescore for flagged rows: coalesced cbT reads, z from LDS.
    // Arithmetic identical to v1: fp32 fma chain per 32-chunk (d ascending,
    // mul start), double chunk-sums ascending, strict-< earliest-k. ----
    for (int fi = 0; fi < nflag; ++fi) {
        const int fm = flag_list[fi];
        zrow_s[t] = x[xbase + (size_t)t * HW + fm];
        __syncthreads();
        float fv = 3.4e38f; int fk = 0;
        double accd[4] = {0.0, 0.0, 0.0, 0.0};
        for (int dc = 0; dc < 8; ++dc) {
            float af[4];
            #pragma unroll
            for (int q = 0; q < 8; ++q) {
                const int d = dc * 32 + q * 4;
                float4 z4 = *(const float4*)&zrow_s[d];     // broadcast
                #pragma unroll
                for (int j = 0; j < 4; ++j) {
                    const int k = j * 256 + t;
                    float e0 = cbT[(size_t)(d + 0) * NUM_K + k];
                    float e1 = cbT[(size_t)(d + 1) * NUM_K + k];
                    float e2 = cbT[(size_t)(d + 2) * NUM_K + k];
                    float e3 = cbT[(size_t)(d + 3) * NUM_K + k];
                    if (q == 0) af[j] = __fmul_rn(z4.x, e0);
                    else        af[j] = fmaf(z4.x, e0, af[j]);
                    af[j] = fmaf(z4.y, e1, af[j]);
                    af[j] = fmaf(z4.z, e2, af[j]);
                    af[j] = fmaf(z4.w, e3, af[j]);
                }
            }
            #pragma unroll
            for (int j = 0; j < 4; ++j) accd[j] += (double)af[j];
        }
        #pragma unroll
        for (int j = 0; j < 4; ++j) {
            const int k = j * 256 + t;          // ascending per thread
            float m32 = (float)accd[j];
            float c   = __fmul_rn(2.0f, m32);
            float t1  = __fadd_rn(Ts_s[fm], u2g[k]);
            float d32 = __fsub_rn(t1, c);
            if (d32 < fv) { fv = d32; fk = k; }
        }
        #pragma unroll
        for (int off = 1; off < 64; off <<= 1) {
            float ov = __shfl_xor(fv, off, 64);
            int   ok = __shfl_xor(fk, off, 64);
            if (ov < fv || (ov == fv && ok < fk)) { fv = ov; fk = ok; }
        }
        if (lane == 0) { rr_v[wv] = fv; rr_k[wv] = fk; }
        __syncthreads();
        if (t == 0) {
            float bfv = rr_v[0]; int bfk = rr_k[0];
            #pragma unroll
            for (int w2 = 1; w2 < 4; ++w2) {
                float v = rr_v[w2]; int k2 = rr_k[w2];
                if (v < bfv || (v == bfv && k2 < bfk)) { bfv = v; bfk = k2; }
            }
            bestk_s[fm] = bfk;
        }
        __syncthreads();   // zrow_s reusable next pass
    }
    __syncthreads();

    if (t < TM) out[IDX_OFF + n0 + t] = (float)bestk_s[t];

    // ---- epilogue: quantized output + fused loss ----
    float lsum = 0.f;
    {
        const int m  = t & 31;
        const int kq = bestk_s[m];
        const float* crow = cb + (size_t)kq * DIM;
        for (int c = (t >> 5); c < DIM; c += 8) {
            float qv = crow[c];
            float xv = x[xbase + (size_t)c * HW + m];
            float d  = qv - xv;
            lsum = fmaf(d, d, lsum);
            out[xbase + (size_t)c * HW + m] = qv;
        }
    }
    #pragma unroll
    for (int off = 32; off > 0; off >>= 1) lsum += __shfl_down(lsum, off, 64);
    if (lane == 0) wsum[wv] = lsum;
    __syncthreads();
    if (t == 0) {
        float s = __fadd_rn(__fadd_rn(wsum[0], wsum[1]), __fadd_rn(wsum[2], wsum[3]));
        atomicAdd(out + LOSS_OFF, s * (1.25f / 8388608.0f));
    }
}

extern "C" void kernel_launch(void* const* d_in, const int* in_sizes, int n_in,
                              void* d_out, int out_size, void* d_ws, size_t ws_size,
                              hipStream_t stream) {
    const float* x  = (const float*)d_in[0];
    const float* cb = (const float*)d_in[1];
    float* out = (float*)d_out;
    float* u2   = (float*)d_ws;                                  // 4 KB
    ushort* ehi = (ushort*)((char*)d_ws + 4096);                 // 512 KB
    float* cbT  = (float*)((char*)d_ws + 4096 + 524288);         // 1 MB

    hipMemsetAsync(out + LOSS_OFF, 0, sizeof(float), stream);
    u2_kernel<<<NUM_K / 256, 256, 0, stream>>>(cb, u2);
    cvt_kernel<<<256, 256, 0, stream>>>(cb, ehi, cbT);
    vq_main<<<N_TOT / TM, 256, 0, stream>>>(x, cb, u2, ehi, cbT, out);
}

// Round 9
// 202.782 us; speedup vs baseline: 4.0632x; 1.5207x over previous
//
#include <hip/hip_runtime.h>

// VectorQuantizer on MI355X — v10: MFMA approx-then-verify (v9 structure) with
// the three measured overheads removed:
//  (1) Ts/u2 row-norms were serial uncoalesced 256-load chains -> j-parallel
//      coalesced scheme reproducing numpy's exact accumulator order.
//  (2) rescore flagged ~30% rows (hi-only MFMA error -> THRESH 2e-4) and
//      re-read 1MB/row -> add elo*zhi MFMA term (error -> ~3.7e-5, 1.2 grid
//      ulp), THRESH=1.25e-4, top-3 tracking: v2-v1>THR done; v3-v1>THR ->
//      2-code cooperative exact rescore; else (rare ~1%) full rescore.
//      Proof: any k with d32<=d32(k1) has d~ <= v1+2e < v1+THR <= v3 =>
//      candidate set subset of {k1,k2}. Ties use exact d32 + earliest-k.
//  (3) epilogue codebook reads vectorized to float4.
// Exact-path arithmetic is v1's verified chain (fp32 fma chain per 32-chunk,
// double chunk-sums ascending, fl32(fl32(T+U)-2*fl32(dot)), strict-< k).
// Geometry: 256 thr (4 waves), TM=32, 1024 blocks. 64 phases of
// [128k x 32d] hi+lo e-tiles (dbuf 32KB) + z hi/lo resident 32KB = 66KB LDS.
// ws: u2 @0 (4KB); ehi @4096 (512KB); elo @528384 (512KB); cbT @1052672 (1MB).

#define NUM_K 1024
#define DIM   256
#define HW    1024
#define N_TOT 32768
#define TM    32
#define LOSS_OFF 8388608
#define IDX_OFF  8388609
#define THR 1.25e-4f

typedef __attribute__((ext_vector_type(8))) short s16x8;
typedef __attribute__((ext_vector_type(4))) float f32x4;
typedef __attribute__((address_space(1))) const char GCHAR;
typedef __attribute__((address_space(3))) char LCHAR;

__device__ __forceinline__ ushort bf16_rne(float f) {
    unsigned u = __float_as_uint(f);
    unsigned r = (u + 0x7FFFu + ((u >> 16) & 1u)) >> 16;
    return (ushort)r;
}

// exact v1 chunk chain: d ascending over 32, mul start
__device__ __forceinline__ float chain32(const float* z, const float* e) {
    float af = __fmul_rn(z[0], e[0]);
    #pragma unroll
    for (int d = 1; d < 32; ++d) af = fmaf(z[d], e[d], af);
    return af;
}

// numpy pairwise combine of 8 accumulators
__device__ __forceinline__ float np_comb8(const float* r) {
    return __fadd_rn(__fadd_rn(__fadd_rn(r[0], r[1]), __fadd_rn(r[2], r[3])),
                     __fadd_rn(__fadd_rn(r[4], r[5]), __fadd_rn(r[6], r[7])));
}

// codebook -> ehi/elo bf16 (row layout) + cbT fp32 transpose. 64 blocks.
__global__ __launch_bounds__(256) void cvt_kernel(const float* __restrict__ cb,
                                                  ushort* __restrict__ ehi,
                                                  ushort* __restrict__ elo,
                                                  float* __restrict__ cbT) {
    __shared__ float tile[64][65];
    const int t  = threadIdx.x;
    const int bk = (blockIdx.x & 15) * 64;   // k tile
    const int bd = (blockIdx.x >> 4) * 64;   // d tile
    #pragma unroll
    for (int rr = 0; rr < 4; ++rr) {
        const int k  = bk + rr * 16 + (t >> 4);
        const int d0 = (t & 15) * 4;
        float4 v = *(const float4*)(cb + (size_t)k * DIM + bd + d0);
        const float* vf = (const float*)&v;
        ushort h[4], l[4];
        #pragma unroll
        for (int j = 0; j < 4; ++j) {
            ushort hb = bf16_rne(vf[j]);
            h[j] = hb;
            l[j] = bf16_rne(vf[j] - __uint_as_float((unsigned)hb << 16));
            tile[d0 + j][rr * 16 + (t >> 4)] = vf[j];
        }
        *(ushort4*)(ehi + (size_t)k * DIM + bd + d0) = make_ushort4(h[0], h[1], h[2], h[3]);
        *(ushort4*)(elo + (size_t)k * DIM + bd + d0) = make_ushort4(l[0], l[1], l[2], l[3]);
    }
    __syncthreads();
    const int dl = t >> 2;
    #pragma unroll
    for (int w = 0; w < 4; ++w) {
        const int kl = (t & 3) * 4 + w * 16;
        float4 o = {tile[dl][kl], tile[dl][kl + 1], tile[dl][kl + 2], tile[dl][kl + 3]};
        *(float4*)(cbT + (size_t)(bd + dl) * NUM_K + bk + kl) = o;
    }
}

// u2 via coalesced cbT, numpy exact order. 32 blocks.
__global__ __launch_bounds__(256) void u2_kernel(const float* __restrict__ cbT,
                                                 float* __restrict__ u2) {
    __shared__ float U[2][8][32];
    const int t = threadIdx.x;
    const int kl = t & 31, j = t >> 5;
    const int k = blockIdx.x * 32 + kl;
    #pragma unroll
    for (int h = 0; h < 2; ++h) {
        const float* bp = cbT + (size_t)(h * 128 + j) * NUM_K + k;
        float a = bp[0];
        float r = __fmul_rn(a, a);
        #pragma unroll
        for (int i = 1; i < 16; ++i) {
            float v = bp[(size_t)(i * 8) * NUM_K];
            r = __fadd_rn(r, __fmul_rn(v, v));
        }
        U[h][j][kl] = r;
    }
    __syncthreads();
    if (t < 32) {
        float s0 = np_comb8(&U[0][0][t] - 0 + 0), s1;
        // gather with stride 32 (U[h][j][t])
        float r0[8], r1[8];
        #pragma unroll
        for (int j2 = 0; j2 < 8; ++j2) { r0[j2] = U[0][j2][t]; r1[j2] = U[1][j2][t]; }
        s0 = np_comb8(r0); s1 = np_comb8(r1);
        u2[blockIdx.x * 32 + t] = __fadd_rn(s0, s1);
    }
}

__global__ __launch_bounds__(256) void vq_main(const float* __restrict__ x,
                                               const float* __restrict__ cb,
                                               const float* __restrict__ u2g,
                                               const ushort* __restrict__ ehi,
                                               const ushort* __restrict__ elo,
                                               const float* __restrict__ cbT,
                                               float* __restrict__ out) {
    __shared__ __align__(16) short z_hi[TM * DIM];       // 16 KB
    __shared__ __align__(16) short z_lo[TM * DIM];       // 16 KB
    __shared__ __align__(16) short ebuf_h[2 * 128 * 32]; // 16 KB
    __shared__ __align__(16) short ebuf_l[2 * 128 * 32]; // 16 KB
    __shared__ float Ts_s[TM];
    __shared__ int   bestk_s[TM];
    __shared__ int   pair_m[TM], pair_k1[TM], pair_k2[TM];
    __shared__ int   full_m[TM];
    __shared__ int   pair_cnt, full_cnt;
    __shared__ float wsum[4];
    // aliases: pre-loop Tred in ebuf_h buf1; post-loop scratch in ebuf_h/l
    float (*Tred)[8][32] = (float (*)[8][32])((char*)ebuf_h + 8192);
    float* red_v1 = (float*)ebuf_h;                       // [128]
    float* red_v2 = (float*)((char*)ebuf_h + 512);
    float* red_v3 = (float*)((char*)ebuf_h + 1024);
    int*   red_k1 = (int*)  ((char*)ebuf_h + 1536);
    int*   red_k2 = (int*)  ((char*)ebuf_h + 2048);
    float* zrow_s = (float*)ebuf_l;                       // [256]
    float* chnk_s = (float*)((char*)ebuf_l + 1024);       // [16]
    float* dp_s   = (float*)((char*)ebuf_l + 1088);       // [2]
    int*   kp_s   = (int*)  ((char*)ebuf_l + 1096);       // [2]
    float* rr_v   = (float*)((char*)ebuf_l + 1104);       // [4]
    int*   rr_k   = (int*)  ((char*)ebuf_l + 1120);       // [4]

    const int t    = threadIdx.x;
    const int lane = t & 63;
    const int wv   = t >> 6;
    const int g    = blockIdx.x;
    const int n0   = g * TM;
    const int b    = n0 >> 10;
    const int r0   = n0 & (HW - 1);
    const size_t xbase = (size_t)b * (DIM * HW) + r0;

    if (t == 0) { pair_cnt = 0; full_cnt = 0; }

    // e staging map (v9-verified): phys slot p4=t&3, row bits (t>>2)&3
    const int q16  = (((t & 3) ^ ((t >> 2) & 3)) << 4);
    const int srow = t >> 2;
    const int wub  = (t & 192) * 16;

    auto stage = [&](int p, int buf) {
        const int ktn = p >> 3, dcn = p & 7;
        #pragma unroll
        for (int j = 0; j < 2; ++j) {
            const size_t ro = (size_t)(ktn * 128 + j * 64 + srow) * 512 + dcn * 64 + q16;
            char* dh = (char*)ebuf_h + buf * 8192 + j * 4096 + wub;
            char* dl = (char*)ebuf_l + buf * 8192 + j * 4096 + wub;
            __builtin_amdgcn_global_load_lds((GCHAR*)((const char*)ehi + ro), (LCHAR*)dh, 16, 0, 0);
            __builtin_amdgcn_global_load_lds((GCHAR*)((const char*)elo + ro), (LCHAR*)dl, 16, 0, 0);
        }
    };

    stage(0, 0);

    // ---- z staging: [d][m] -> [m][oct] bf16 hi/lo, oct-XOR swizzle ----
    {
        const int oct = t >> 3;
        const int zd0 = oct * 8;
        const int zm0 = (t & 7) * 4;
        float4 xv[8];
        #pragma unroll
        for (int dd = 0; dd < 8; ++dd)
            xv[dd] = *(const float4*)(x + xbase + (size_t)(zd0 + dd) * HW + zm0);
        #pragma unroll
        for (int j = 0; j < 4; ++j) {
            const int m = zm0 + j;
            s16x8 hv, lv;
            #pragma unroll
            for (int dd = 0; dd < 8; ++dd) {
                float f = ((const float*)&xv[dd])[j];
                ushort hb = bf16_rne(f);
                hv[dd] = (short)hb;
                lv[dd] = (short)bf16_rne(f - __uint_as_float((unsigned)hb << 16));
            }
            const int byte = m * 512 + (((oct ^ m) & 31) << 4);
            *(s16x8*)((char*)z_hi + byte) = hv;
            *(s16x8*)((char*)z_lo + byte) = lv;
        }
    }

    // ---- Ts: numpy-order row norms, j-parallel coalesced ----
    {
        const int m_ = t & 31, j_ = t >> 5;   // 8 j's x 32 m
        #pragma unroll
        for (int h = 0; h < 2; ++h) {
            const float* bp = x + xbase + (size_t)(h * 128 + j_) * HW + m_;
            float a = bp[0];
            float r = __fmul_rn(a, a);
            #pragma unroll
            for (int i = 1; i < 16; ++i) {
                float v = bp[(size_t)(i * 8) * HW];
                r = __fadd_rn(r, __fmul_rn(v, v));
            }
            (*Tred)[0][0] = (*Tred)[0][0];   // no-op keep array live
            Tred[h][j_][m_] = r;
        }
    }
    __syncthreads();
    if (t < 32) {
        float r0a[8], r1a[8];
        #pragma unroll
        for (int j2 = 0; j2 < 8; ++j2) { r0a[j2] = Tred[0][j2][t]; r1a[j2] = Tred[1][j2][t]; }
        Ts_s[t] = __fadd_rn(np_comb8(r0a), np_comb8(r1a));
    }
    __syncthreads();

    // ---- per-lane geometry (v9-verified) ----
    const int col  = lane & 15;
    const int lg   = lane >> 4;
    const int ebA  = (wv * 32 + col) * 64;
    const int ebB  = ebA + 16 * 64;
    const int eswz = (col & 3) << 4;
    const int zmA  = col, zmB = col + 16;
    const float TsA = Ts_s[zmA];
    const float TsB = Ts_s[zmB];

    // top-3 tracking per m-stream
    float vA1 = 3.4e38f, vA2 = 3.4e38f, vA3 = 3.4e38f; int kA1 = 0, kA2 = 0;
    float vB1 = 3.4e38f, vB2 = 3.4e38f, vB3 = 3.4e38f; int kB1 = 0, kB2 = 0;

    for (int kt = 0; kt < 8; ++kt) {
        f32x4 a00 = {0,0,0,0}, a01 = {0,0,0,0}, a10 = {0,0,0,0}, a11 = {0,0,0,0};

        for (int dc = 0; dc < 8; ++dc) {
            const int p = kt * 8 + dc;
            __syncthreads();
            if (p + 1 < 64) stage(p + 1, (p + 1) & 1);
            const char* eph = (const char*)ebuf_h + (p & 1) * 8192;
            const char* epl = (const char*)ebuf_l + (p & 1) * 8192;

            const int eoff = (lg << 4) ^ eswz;
            s16x8 eh0 = *(const s16x8*)(eph + ebA + eoff);
            s16x8 eh1 = *(const s16x8*)(eph + ebB + eoff);
            s16x8 el0 = *(const s16x8*)(epl + ebA + eoff);
            s16x8 el1 = *(const s16x8*)(epl + ebB + eoff);
            const int oct = dc * 4 + lg;
            const int zoA = zmA * 512 + (((oct ^ zmA) & 31) << 4);
            const int zoB = zmB * 512 + (((oct ^ zmB) & 31) << 4);
            s16x8 zh0 = *(const s16x8*)((const char*)z_hi + zoA);
            s16x8 zl0 = *(const s16x8*)((const char*)z_lo + zoA);
            s16x8 zh1 = *(const s16x8*)((const char*)z_hi + zoB);
            s16x8 zl1 = *(const s16x8*)((const char*)z_lo + zoB);
            // 3-term split: ehi*zhi + ehi*zlo + elo*zhi
            a00 = __builtin_amdgcn_mfma_f32_16x16x32_bf16(eh0, zh0, a00, 0, 0, 0);
            a00 = __builtin_amdgcn_mfma_f32_16x16x32_bf16(eh0, zl0, a00, 0, 0, 0);
            a00 = __builtin_amdgcn_mfma_f32_16x16x32_bf16(el0, zh0, a00, 0, 0, 0);
            a01 = __builtin_amdgcn_mfma_f32_16x16x32_bf16(eh0, zh1, a01, 0, 0, 0);
            a01 = __builtin_amdgcn_mfma_f32_16x16x32_bf16(eh0, zl1, a01, 0, 0, 0);
            a01 = __builtin_amdgcn_mfma_f32_16x16x32_bf16(el0, zh1, a01, 0, 0, 0);
            a10 = __builtin_amdgcn_mfma_f32_16x16x32_bf16(eh1, zh0, a10, 0, 0, 0);
            a10 = __builtin_amdgcn_mfma_f32_16x16x32_bf16(eh1, zl0, a10, 0, 0, 0);
            a10 = __builtin_amdgcn_mfma_f32_16x16x32_bf16(el1, zh0, a10, 0, 0, 0);
            a11 = __builtin_amdgcn_mfma_f32_16x16x32_bf16(eh1, zh1, a11, 0, 0, 0);
            a11 = __builtin_amdgcn_mfma_f32_16x16x32_bf16(eh1, zl1, a11, 0, 0, 0);
            a11 = __builtin_amdgcn_mfma_f32_16x16x32_bf16(el1, zh1, a11, 0, 0, 0);
        }

        // ---- kt epilogue: d~ + top-3 update ----
        const int kb = kt * 128 + wv * 32 + lg * 4;
        float4 u40 = *(const float4*)(u2g + kb);
        float4 u41 = *(const float4*)(u2g + kb + 16);
        const float* u0f = (const float*)&u40;
        const float* u1f = (const float*)&u41;
        #pragma unroll
        for (int s = 0; s < 2; ++s) {
            const f32x4 aa = s ? a10 : a00;
            const f32x4 ab = s ? a11 : a01;
            const float* uf = s ? u1f : u0f;
            #pragma unroll
            for (int r = 0; r < 4; ++r) {
                const int kk = kb + s * 16 + r;
                float c, t1, d32;
                c = __fmul_rn(2.0f, aa[r]); t1 = __fadd_rn(TsA, uf[r]); d32 = __fsub_rn(t1, c);
                if (d32 < vA1)      { vA3 = vA2; vA2 = vA1; kA2 = kA1; vA1 = d32; kA1 = kk; }
                else if (d32 < vA2) { vA3 = vA2; vA2 = d32; kA2 = kk; }
                else if (d32 < vA3) { vA3 = d32; }
                c = __fmul_rn(2.0f, ab[r]); t1 = __fadd_rn(TsB, uf[r]); d32 = __fsub_rn(t1, c);
                if (d32 < vB1)      { vB3 = vB2; vB2 = vB1; kB2 = kB1; vB1 = d32; kB1 = kk; }
                else if (d32 < vB2) { vB3 = vB2; vB2 = d32; kB2 = kk; }
                else if (d32 < vB3) { vB3 = d32; }
            }
        }
    }

    __syncthreads();   // last phase reads done -> aliases safe

    // ---- merge top-3 across the 4 lane-groups (disjoint k-sets) ----
    #pragma unroll
    for (int off = 16; off < 64; off <<= 1) {
        {
            float a1 = __shfl_xor(vA1, off, 64), a2 = __shfl_xor(vA2, off, 64), a3 = __shfl_xor(vA3, off, 64);
            int  ka1 = __shfl_xor(kA1, off, 64), ka2 = __shfl_xor(kA2, off, 64);
            if (a1 < vA1 || (a1 == vA1 && ka1 < kA1)) {
                if (vA1 < a2 || (vA1 == a2 && kA1 < ka2)) { vA3 = fminf(vA2, a2); vA2 = vA1; kA2 = kA1; }
                else { vA3 = fminf(vA1, a3); vA2 = a2; kA2 = ka2; }
                vA1 = a1; kA1 = ka1;
            } else {
                if (a1 < vA2 || (a1 == vA2 && ka1 < kA2)) { vA3 = fminf(vA2, a2); vA2 = a1; kA2 = ka1; }
                else { vA3 = fminf(vA3, a1); }
            }
        }
        {
            float a1 = __shfl_xor(vB1, off, 64), a2 = __shfl_xor(vB2, off, 64), a3 = __shfl_xor(vB3, off, 64);
            int  ka1 = __shfl_xor(kB1, off, 64), ka2 = __shfl_xor(kB2, off, 64);
            if (a1 < vB1 || (a1 == vB1 && ka1 < kB1)) {
                if (vB1 < a2 || (vB1 == a2 && kB1 < ka2)) { vB3 = fminf(vB2, a2); vB2 = vB1; kB2 = kB1; }
                else { vB3 = fminf(vB1, a3); vB2 = a2; kB2 = ka2; }
                vB1 = a1; kB1 = ka1;
            } else {
                if (a1 < vB2 || (a1 == vB2 && ka1 < kB2)) { vB3 = fminf(vB2, a2); vB2 = a1; kB2 = ka1; }
                else { vB3 = fminf(vB3, a1); }
            }
        }
    }
    if (lane < 16) {
        red_v1[wv * 32 + zmA] = vA1; red_v2[wv * 32 + zmA] = vA2; red_v3[wv * 32 + zmA] = vA3;
        red_k1[wv * 32 + zmA] = kA1; red_k2[wv * 32 + zmA] = kA2;
        red_v1[wv * 32 + zmB] = vB1; red_v2[wv * 32 + zmB] = vB2; red_v3[wv * 32 + zmB] = vB3;
        red_k1[wv * 32 + zmB] = kB1; red_k2[wv * 32 + zmB] = kB2;
    }
    __syncthreads();

    // ---- per-m merge across 4 waves + classify ----
    if (t < TM) {
        float b1 = red_v1[t], b2 = red_v2[t], b3 = red_v3[t];
        int  bk1 = red_k1[t], bk2 = red_k2[t];
        #pragma unroll
        for (int q = 1; q < 4; ++q) {
            float a1 = red_v1[q * 32 + t], a2 = red_v2[q * 32 + t], a3 = red_v3[q * 32 + t];
            int  ka1 = red_k1[q * 32 + t], ka2 = red_k2[q * 32 + t];
            if (a1 < b1 || (a1 == b1 && ka1 < bk1)) {
                if (b1 < a2 || (b1 == a2 && bk1 < ka2)) { b3 = fminf(b2, a2); b2 = b1; bk2 = bk1; }
                else { b3 = fminf(b1, a3); b2 = a2; bk2 = ka2; }
                b1 = a1; bk1 = ka1;
            } else {
                if (a1 < b2 || (a1 == b2 && ka1 < bk2)) { b3 = fminf(b2, a2); b2 = a1; bk2 = ka1; }
                else { b3 = fminf(b3, a1); }
            }
        }
        bestk_s[t] = bk1;
        if (b2 - b1 < THR) {
            if (b3 - b1 < THR) { int s = atomicAdd(&full_cnt, 1); full_m[s] = t; }
            else { int s = atomicAdd(&pair_cnt, 1); pair_m[s] = t; pair_k1[s] = bk1; pair_k2[s] = bk2; }
        }
    }
    __syncthreads();
    const int npair = pair_cnt, nfull = full_cnt;

    // ---- pair rescore: exact d32 for {k1,k2}, cooperative per row ----
    for (int fi = 0; fi < npair; ++fi) {
        const int fm = pair_m[fi];
        zrow_s[t] = x[xbase + (size_t)t * HW + fm];
        __syncthreads();
        if (t < 16) {
            const int k = (t & 8) ? pair_k2[fi] : pair_k1[fi];
            chnk_s[t] = chain32(zrow_s + (t & 7) * 32, cb + (size_t)k * DIM + (t & 7) * 32);
        }
        __syncthreads();
        if (t < 2) {
            const int k = t ? pair_k2[fi] : pair_k1[fi];
            double acc = 0.0;
            #pragma unroll
            for (int c = 0; c < 8; ++c) acc += (double)chnk_s[t * 8 + c];
            float m32 = (float)acc;
            float c2  = __fmul_rn(2.0f, m32);
            float t1  = __fadd_rn(Ts_s[fm], u2g[k]);
            dp_s[t] = __fsub_rn(t1, c2);
            kp_s[t] = k;
        }
        __syncthreads();
        if (t == 0) {
            float dA = dp_s[0], dB = dp_s[1]; int kA = kp_s[0], kB = kp_s[1];
            bestk_s[fm] = (dB < dA || (dB == dA && kB < kA)) ? kB : kA;
        }
        __syncthreads();
    }

    // ---- full rescore (rare): v9's coalesced cbT path ----
    for (int fi = 0; fi < nfull; ++fi) {
        const int fm = full_m[fi];
        zrow_s[t] = x[xbase + (size_t)t * HW + fm];
        __syncthreads();
        float fv = 3.4e38f; int fk = 0;
        double accd[4] = {0.0, 0.0, 0.0, 0.0};
        for (int dc = 0; dc < 8; ++dc) {
            float af[4];
            #pragma unroll
            for (int q = 0; q < 8; ++q) {
                const int d = dc * 32 + q * 4;
                float4 z4 = *(const float4*)&zrow_s[d];
                #pragma unroll
                for (int j = 0; j < 4; ++j) {
                    const int k = j * 256 + t;
                    float e0 = cbT[(size_t)(d + 0) * NUM_K + k];
                    float e1 = cbT[(size_t)(d + 1) * NUM_K + k];
                    float e2 = cbT[(size_t)(d + 2) * NUM_K + k];
                    float e3 = cbT[(size_t)(d + 3) * NUM_K + k];
                    if (q == 0) af[j] = __fmul_rn(z4.x, e0);
                    else        af[j] = fmaf(z4.x, e0, af[j]);
                    af[j] = fmaf(z4.y, e1, af[j]);
                    af[j] = fmaf(z4.z, e2, af[j]);
                    af[j] = fmaf(z4.w, e3, af[j]);
                }
            }
            #pragma unroll
            for (int j = 0; j < 4; ++j) accd[j] += (double)af[j];
        }
        #pragma unroll
        for (int j = 0; j < 4; ++j) {
            const int k = j * 256 + t;
            float m32 = (float)accd[j];
            float c2  = __fmul_rn(2.0f, m32);
            float t1  = __fadd_rn(Ts_s[fm], u2g[k]);
            float d32 = __fsub_rn(t1, c2);
            if (d32 < fv) { fv = d32; fk = k; }
        }
        #pragma unroll
        for (int off = 1; off < 64; off <<= 1) {
            float ov = __shfl_xor(fv, off, 64);
            int   ok = __shfl_xor(fk, off, 64);
            if (ov < fv || (ov == fv && ok < fk)) { fv = ov; fk = ok; }
        }
        if (lane == 0) { rr_v[wv] = fv; rr_k[wv] = fk; }
        __syncthreads();
        if (t == 0) {
            float bfv = rr_v[0]; int bfk = rr_k[0];
            #pragma unroll
            for (int w2 = 1; w2 < 4; ++w2) {
                float v = rr_v[w2]; int k2 = rr_k[w2];
                if (v < bfv || (v == bfv && k2 < bfk)) { bfv = v; bfk = k2; }
            }
            bestk_s[fm] = bfk;
        }
        __syncthreads();
    }
    __syncthreads();

    if (t < TM) out[IDX_OFF + n0 + t] = (float)bestk_s[t];

    // ---- epilogue: quantized output + fused loss (float4 crow) ----
    float lsum = 0.f;
    {
        const int m  = t & 31;
        const int kq = bestk_s[m];
        const float* crow = cb + (size_t)kq * DIM;
        const int c0 = t >> 5;             // 0..7
        #pragma unroll
        for (int j = 0; j < 8; ++j) {
            const int c4 = c0 + j * 8;     // float4 chunk index 0..63
            float4 qv = *(const float4*)(crow + c4 * 4);
            const float* qf = (const float*)&qv;
            #pragma unroll
            for (int jj = 0; jj < 4; ++jj) {
                const int c = c4 * 4 + jj;
                float xv = x[xbase + (size_t)c * HW + m];
                float d  = qf[jj] - xv;
                lsum = fmaf(d, d, lsum);
                out[xbase + (size_t)c * HW + m] = qf[jj];
            }
        }
    }
    #pragma unroll
    for (int off = 32; off > 0; off >>= 1) lsum += __shfl_down(lsum, off, 64);
    if (lane == 0) wsum[wv] = lsum;
    __syncthreads();
    if (t == 0) {
        float s = __fadd_rn(__fadd_rn(wsum[0], wsum[1]), __fadd_rn(wsum[2], wsum[3]));
        atomicAdd(out + LOSS_OFF, s * (1.25f / 8388608.0f));
    }
}

extern "C" void kernel_launch(void* const* d_in, const int* in_sizes, int n_in,
                              void* d_out, int out_size, void* d_ws, size_t ws_size,
                              hipStream_t stream) {
    const float* x  = (const float*)d_in[0];
    const float* cb = (const float*)d_in[1];
    float* out = (float*)d_out;
    float*  u2  = (float*) d_ws;                                    // 4 KB
    ushort* ehi = (ushort*)((char*)d_ws + 4096);                    // 512 KB
    ushort* elo = (ushort*)((char*)d_ws + 528384);                  // 512 KB
    float*  cbT = (float*) ((char*)d_ws + 1052672);                 // 1 MB

    hipMemsetAsync(out + LOSS_OFF, 0, sizeof(float), stream);
    cvt_kernel<<<64, 256, 0, stream>>>(cb, ehi, elo, cbT);
    u2_kernel<<<32, 256, 0, stream>>>(cbT, u2);
    vq_main<<<N_TOT / TM, 256, 0, stream>>>(x, cb, u2, ehi, elo, cbT, out);
}